// Round 11
// baseline (422.182 us; speedup 1.0000x reference)
//
#include <hip/hip_runtime.h>
#include <hip/hip_bf16.h>

// ---------------------------------------------------------------------------
// AttentionBase: out = softmax((in@Wq^T+bq)*ds @ (mem@Wk^T+bk)^T) @ (mem@Wv^T+bv) @ Wo^T + bo
// B=8, S=2048, C=1024. All matmuls bf16 MFMA gemm_bt on a BRICK layout.
// Brick: per 128-row tile, per 32-k slice, element (r,k) at
//   r*32 + ((((k>>3)&3) ^ ((r>>1)&3))<<3) + (k&7)   (granule swizzle baked in).
// GEMM core: NO LDS, NO barriers — fragments stream global->VGPR directly
// (2-deep statically-indexed register double buffer, compiler-scheduled
// waitcnts, waves fully independent). Templated wave tile: 4x8 frags
// (128x256 block) for K=1024 GEMMs (AI=87 FLOP/L2-byte), 4x4 for PV.
// cvt: lane-paired transpose (lane 2i/2i+1 = rows r/r+1 at k-slice i) ->
// reads are full 4KB row streams, writes are 128B full lines.
// PV row-sums via ones-operand MFMA. d_out doubles as scratch (Vt | inb).
// ---------------------------------------------------------------------------

typedef __attribute__((ext_vector_type(8))) short short8;   // 8 bf16 = 4 VGPRs
typedef __attribute__((ext_vector_type(4))) float f32x4;

static __device__ __forceinline__ unsigned short f2bf(float f) {
  union { float f; unsigned u; } x; x.f = f;
  unsigned r = x.u + 0x7FFFu + ((x.u >> 16) & 1u);   // round-to-nearest-even
  return (unsigned short)(r >> 16);
}

// brick element offset for element (row r_, k k_) in a brick file of depth Kd
static __device__ __forceinline__ long long brickoff(int r_, int k_, int Kd) {
  return (long long)(r_ >> 7) * ((long long)128 * Kd) +
         (long long)(k_ >> 5) * 4096 +
         (r_ & 127) * 32 +
         (((((k_ >> 3) & 3) ^ ((r_ >> 1) & 3))) << 3) +
         (k_ & 7);
}

// f32 row-major [16384][1024] -> bf16 bricks (Kd=1024); two tensors per launch.
// Wave w handles (tile = w>>6, row pair rbase = (w&63)*2); lane 2i/2i+1 do
// rows rbase/rbase+1 at k-slice i. Reads: 2 full 4KB rows per wave (stream).
// Writes: lane pairs -> adjacent 64B brick rows = 128B lines.
__global__ __launch_bounds__(256) void cvt_brick_kernel(
    const float* __restrict__ s0, const float* __restrict__ s1,
    unsigned short* __restrict__ o0, unsigned short* __restrict__ o1) {
  const float* src = blockIdx.y ? s1 : s0;
  unsigned short* dst = blockIdx.y ? o1 : o0;
  const int gid = blockIdx.x * 256 + threadIdx.x;   // 2048*256 = 8192 waves exact
  const int wv = gid >> 6;
  const int lane = gid & 63;
  const int tile = wv >> 6;                         // 128 tiles
  const int r = (wv & 63) * 2 + (lane & 1);
  const int ks = lane >> 1;                         // 0..31
  const float* sp = src + (long long)(tile * 128 + r) * 1024 + ks * 32;
  float4 u[8];
#pragma unroll
  for (int i = 0; i < 8; ++i) u[i] = ((const float4*)sp)[i];
  const int x = (r >> 1) & 3;
  unsigned short* dp = dst + (long long)tile * 131072 + ks * 4096 + r * 32;
#pragma unroll
  for (int p = 0; p < 4; ++p) {
    const int g = p ^ x;
    short8 pk;
    pk[0] = (short)f2bf(u[2*g].x);   pk[1] = (short)f2bf(u[2*g].y);
    pk[2] = (short)f2bf(u[2*g].z);   pk[3] = (short)f2bf(u[2*g].w);
    pk[4] = (short)f2bf(u[2*g+1].x); pk[5] = (short)f2bf(u[2*g+1].y);
    pk[6] = (short)f2bf(u[2*g+1].z); pk[7] = (short)f2bf(u[2*g+1].w);
    *(short8*)(dp + p * 8) = pk;
  }
}

// all four C*C weights f32 -> bricks in one launch (blockIdx.y selects)
__global__ __launch_bounds__(256) void wcvt_brick_kernel(
    const float* __restrict__ w0, const float* __restrict__ w1,
    const float* __restrict__ w2, const float* __restrict__ w3,
    unsigned short* __restrict__ o0, unsigned short* __restrict__ o1,
    unsigned short* __restrict__ o2, unsigned short* __restrict__ o3) {
  const float* src; unsigned short* dst;
  switch (blockIdx.y) {
    case 0: src = w0; dst = o0; break;
    case 1: src = w1; dst = o1; break;
    case 2: src = w2; dst = o2; break;
    default: src = w3; dst = o3; break;
  }
  const int gid = blockIdx.x * 256 + threadIdx.x;   // 512*256 = 131072 exact
  const int tile = gid >> 14;
  const int g2 = gid & 16383;
  const int ks = g2 >> 9;
  const int rp = g2 & 511;
  const int r = rp >> 2;
  const int p = rp & 3;
  const int g = p ^ ((r >> 1) & 3);
  const float* sp = src + (long long)(tile * 128 + r) * 1024 + ks * 32 + g * 8;
  float4 u0 = ((const float4*)sp)[0];
  float4 u1 = ((const float4*)sp)[1];
  short8 pk;
  pk[0] = (short)f2bf(u0.x); pk[1] = (short)f2bf(u0.y);
  pk[2] = (short)f2bf(u0.z); pk[3] = (short)f2bf(u0.w);
  pk[4] = (short)f2bf(u1.x); pk[5] = (short)f2bf(u1.y);
  pk[6] = (short)f2bf(u1.z); pk[7] = (short)f2bf(u1.w);
  *(short8*)&dst[(long long)gid * 8] = pk;
}

#define EPI_BF16 0        // brick write, Kd = ldd
#define EPI_BF16_TRANS 1  // brick write transposed (Vt), Kd = ldd
#define EPI_EXP 2         // brick write exp(acc), Kd = ldd
#define EPI_PV 3          // brick write acc/rowsum, Kd = ldd
#define EPI_F32 4         // row-major f32, ld = ldd

// D = epilogue(A x B^T (+bias)(*scale)); A,B are BRICK files. No LDS.
// Block = (MFR*32) x (NFR*32), 4 waves 2x2, each wave MFR x NFR 16x16 frags.
// ldaK/ldbK: brick K-depth. sA/sBflat: flat batch offsets. sBslice/kOffB:
// per-z / constant B k-slice offsets. NT: K/32 slices (even).
template <int MFR, int NFR, int EPI, bool HAS_BIAS>
__global__ __launch_bounds__(256, (MFR * NFR >= 32) ? 2 : 3) void gemm_kernel(
    const unsigned short* __restrict__ A, const unsigned short* __restrict__ B,
    const float* __restrict__ bias, void* __restrict__ Dv,
    int NT, int ldaK, int ldbK, int ldd,
    long long sA, long long sBflat, int sBslice, int kOffB,
    long long sD, float scale) {
  constexpr int BM = MFR * 32;
  constexpr int BN = NFR * 32;

  // ---- XCD chunk swizzle (nwg % 8 == 0) ----
  int i = blockIdx.x + gridDim.x * (blockIdx.y + gridDim.y * blockIdx.z);
  const int nwg = gridDim.x * gridDim.y * gridDim.z;
  int v = (i & 7) * (nwg >> 3) + (i >> 3);
  const int by = v % gridDim.y;
  int u = v / gridDim.y;
  const int bx = u % gridDim.x;
  const int bz = u / gridDim.x;

  const int bm = bx * BM;
  const int bn = by * BN;
  const int tid = threadIdx.x;
  const int lane = tid & 63;
  const int wid = tid >> 6;
  const int wr = (wid >> 1) * (MFR * 16);
  const int wc = (wid & 1) * (NFR * 16);
  const int fr = lane & 15;
  const int hi = lane >> 4;
  // per-lane offset inside a fragment's contiguous 1KB block (intra-1KB perm)
  const int laneoff = fr * 32 + ((hi ^ ((fr >> 1) & 3)) << 3);

  f32x4 acc[MFR][NFR];
#pragma unroll
  for (int m = 0; m < MFR; ++m)
#pragma unroll
    for (int n = 0; n < NFR; ++n) acc[m][n] = (f32x4){0.f, 0.f, 0.f, 0.f};

  f32x4 asum[MFR];
  short8 ones;
#pragma unroll
  for (int m = 0; m < MFR; ++m) asum[m] = (f32x4){0.f, 0.f, 0.f, 0.f};
#pragma unroll
  for (int j = 0; j < 8; ++j) ones[j] = (short)0x3F80;  // bf16 1.0

  // wave's frags sit within ONE 128-row brick tile on each side:
  const unsigned short* Ap = A + bz * sA +
      (long long)((bm + wr) >> 7) * 128 * ldaK + (wr & 127) * 32 + laneoff;
  const unsigned short* Bp = B + bz * sBflat +
      (long long)((bn + wc) >> 7) * 128 * ldbK +
      (long long)(kOffB + bz * sBslice) * 4096 + (wc & 127) * 32 + laneoff;

  // 2-deep register double buffer, all statically indexed (rule #20)
  short8 a0[MFR], b0[NFR], a1[MFR], b1[NFR];
  auto LDA = [&](short8 (&d)[MFR], int t) {
    const unsigned short* p = Ap + (long long)t * 4096;
#pragma unroll
    for (int m = 0; m < MFR; ++m) d[m] = *(const short8*)(p + m * 512);
  };
  auto LDB = [&](short8 (&d)[NFR], int t) {
    const unsigned short* p = Bp + (long long)t * 4096;
#pragma unroll
    for (int n = 0; n < NFR; ++n) d[n] = *(const short8*)(p + n * 512);
  };
  auto FMA = [&](short8 (&a)[MFR], short8 (&b)[NFR]) {
#pragma unroll
    for (int m = 0; m < MFR; ++m)
#pragma unroll
      for (int n = 0; n < NFR; ++n)
        acc[m][n] = __builtin_amdgcn_mfma_f32_16x16x32_bf16(a[m], b[n],
                                                            acc[m][n], 0, 0, 0);
    if (EPI == EPI_PV) {
#pragma unroll
      for (int m = 0; m < MFR; ++m)
        asum[m] = __builtin_amdgcn_mfma_f32_16x16x32_bf16(a[m], ones,
                                                          asum[m], 0, 0, 0);
    }
  };

  LDA(a0, 0); LDB(b0, 0);
  LDA(a1, 1); LDB(b1, 1);
  for (int t = 0; t < NT - 2; t += 2) {
    FMA(a0, b0);
    LDA(a0, t + 2); LDB(b0, t + 2);
    FMA(a1, b1);
    LDA(a1, t + 3); LDB(b1, t + 3);
  }
  FMA(a0, b0);
  FMA(a1, b1);

  // ---- epilogue: C/D frag layout col=lane&15, row=(lane>>4)*4+j ----
  const int cr = hi * 4;
  const int cc = fr;
#pragma unroll
  for (int m = 0; m < MFR; ++m) {
    const int row0 = bm + wr + m * 16 + cr;
#pragma unroll
    for (int n = 0; n < NFR; ++n) {
      const int col = bn + wc + n * 16 + cc;
      const float bv = HAS_BIAS ? bias[col] : 0.f;
      if (EPI == EPI_F32) {
        float* D = (float*)Dv + bz * sD;
#pragma unroll
        for (int j = 0; j < 4; ++j)
          D[(long long)(row0 + j) * ldd + col] = acc[m][n][j] + bv;
      } else if (EPI == EPI_BF16) {
        unsigned short* D = (unsigned short*)Dv + bz * sD;
#pragma unroll
        for (int j = 0; j < 4; ++j)
          D[brickoff(row0 + j, col, ldd)] = f2bf((acc[m][n][j] + bv) * scale);
      } else if (EPI == EPI_BF16_TRANS) {
        unsigned short* D = (unsigned short*)Dv + bz * sD;
#pragma unroll
        for (int j = 0; j < 4; ++j)
          D[brickoff(col, row0 + j, ldd)] = f2bf((acc[m][n][j] + bv) * scale);
      } else if (EPI == EPI_EXP) {
        unsigned short* D = (unsigned short*)Dv + bz * sD;
#pragma unroll
        for (int j = 0; j < 4; ++j)
          D[brickoff(row0 + j, col, ldd)] = f2bf(__expf(acc[m][n][j]));
      } else {  // EPI_PV
        unsigned short* D = (unsigned short*)Dv + bz * sD;
#pragma unroll
        for (int j = 0; j < 4; ++j) {
          const float li = 1.f / asum[m][j];
          D[brickoff(row0 + j, col, ldd)] = f2bf(acc[m][n][j] * li);
        }
      }
    }
  }
}

extern "C" void kernel_launch(void* const* d_in, const int* in_sizes, int n_in,
                              void* d_out, int out_size, void* d_ws, size_t ws_size,
                              hipStream_t stream) {
  (void)in_sizes; (void)n_in; (void)out_size;
  const float* input  = (const float*)d_in[0];
  const float* memory = (const float*)d_in[1];
  const float* Wq = (const float*)d_in[2];
  const float* bq = (const float*)d_in[3];
  const float* Wk = (const float*)d_in[4];
  const float* bk = (const float*)d_in[5];
  const float* Wv = (const float*)d_in[6];
  const float* bv = (const float*)d_in[7];
  const float* Wo = (const float*)d_in[8];
  const float* bo = (const float*)d_in[9];
  float* out = (float*)d_out;

  const int S = 2048, C = 1024;
  const int CB = 4;
  const long long BS = 16384;
  const long long N_IN = BS * C;        // 16,777,216
  const long long N_W  = (long long)C * C;

  char* p = (char*)d_ws;
  auto alloc = [&](size_t bytes) {
    char* r = p;
    p += (bytes + 255) & ~(size_t)255;
    return r;
  };
  unsigned short* wqb  = (unsigned short*)alloc(N_W * 2);
  unsigned short* wkb  = (unsigned short*)alloc(N_W * 2);
  unsigned short* wvb  = (unsigned short*)alloc(N_W * 2);
  unsigned short* wob  = (unsigned short*)alloc(N_W * 2);
  unsigned short* Qb   = (unsigned short*)alloc(N_IN * 2);   // bricks Kd=1024; later sel
  unsigned short* Kb   = (unsigned short*)alloc(N_IN * 2);   // bricks Kd=1024
  unsigned short* Xb   = (unsigned short*)alloc(N_IN * 2);   // memb bricks, then Pt
  if ((size_t)(p - (char*)d_ws) > ws_size) return;

  unsigned short* Vt  = (unsigned short*)d_out;          // V bricks (rows=c, Kd=16384)
  unsigned short* inb = (unsigned short*)d_out + N_IN;   // input bricks Kd=1024
  unsigned short* memb = Xb;
  unsigned short* Pt   = Xb;                             // P~ bricks Kd=2048 (CB batches)

  // ---- f32 -> bf16 bricks ----
  wcvt_brick_kernel<<<dim3(512, 4, 1), 256, 0, stream>>>(Wq, Wk, Wv, Wo,
                                                         wqb, wkb, wvb, wob);
  cvt_brick_kernel<<<dim3(2048, 2, 1), 256, 0, stream>>>(memory, input, memb, inb);

  const float depth_scale = 0.03125f;  // 1024^-0.5

  // ---- projections (NT=32): 128x256 blocks, grid (128,4)=512 ----
  gemm_kernel<4, 8, EPI_BF16, true><<<dim3(128, 4, 1), 256, 0, stream>>>(
      memb, wkb, bk, Kb, 32, C, C, C, 0, 0, 0, 0, 0, 1.0f);
  gemm_kernel<4, 8, EPI_BF16_TRANS, true><<<dim3(128, 4, 1), 256, 0, stream>>>(
      memb, wvb, bv, Vt, 32, C, C, (int)BS, 0, 0, 0, 0, 0, 1.0f);
  gemm_kernel<4, 8, EPI_BF16, true><<<dim3(128, 4, 1), 256, 0, stream>>>(
      inb, wqb, bq, Qb, 32, C, C, C, 0, 0, 0, 0, 0, depth_scale);

  // ---- attention, CB=4 batches per chunk (memb dead -> Pt) ----
  for (int c = 0; c < 8 / CB; ++c) {
    const long long qoff = (long long)c * CB * S * C;
    // P~ = exp(Q[b] @ K[b]^T) -> Pt bricks Kd=2048; grid (16,8,4)=512
    gemm_kernel<4, 8, EPI_EXP, false><<<dim3(16, 8, CB), 256, 0, stream>>>(
        Qb + qoff, Kb + qoff, nullptr, Pt,
        32, C, C, S, (long long)S * C, (long long)S * C, 0, 0,
        (long long)S * S, 1.0f);
    // sel[b] = (P~ @ V[b]) / rowsum -> sel bricks over dead Q rows; grid (16,8,4)=512
    gemm_kernel<4, 4, EPI_PV, false><<<dim3(16, 8, CB), 256, 0, stream>>>(
        Pt, Vt, nullptr, Qb + qoff,
        64, S, (int)BS, C, (long long)S * S, 0, 64, c * CB * 64,
        (long long)S * C, 1.0f);
  }

  // ---- out = sel @ Wo^T + bo -> f32 row-major d_out ----
  gemm_kernel<4, 8, EPI_F32, true><<<dim3(128, 4, 1), 256, 0, stream>>>(
      Qb, wob, bo, out, 32, C, C, C, 0, 0, 0, 0, 0, 1.0f);
}

// Round 12
// 378.913 us; speedup vs baseline: 1.1142x; 1.1142x over previous
//
#include <hip/hip_runtime.h>
#include <hip/hip_bf16.h>

// ---------------------------------------------------------------------------
// AttentionBase: out = softmax((in@Wq^T+bq)*ds @ (mem@Wk^T+bk)^T) @ (mem@Wv^T+bv) @ Wo^T + bo
// B=8, S=2048, C=1024. All matmuls bf16 MFMA gemm_bt on a BRICK layout.
// Brick: per 128-row tile, per 32-k slice, element (r,k) at
//   r*32 + ((((k>>3)&3) ^ ((r>>1)&3))<<3) + (k&7)   (granule swizzle baked in).
// GEMM core: NO LDS, NO barriers — fragments stream global->VGPR directly
// (2-deep statically-indexed register double buffer, compiler-scheduled
// waitcnts, waves fully independent). Wave tile 4x8 frags (128x256 block)
// for K=1024 GEMMs, 4x4 for PV.
// cvt (r10 version): writes are gid*16B fully contiguous per instruction
// (r11's lane-paired variant caused 3x write amplification — reverted).
// PV row-sums via ones-operand MFMA. d_out doubles as scratch (Vt | inb).
// ---------------------------------------------------------------------------

typedef __attribute__((ext_vector_type(8))) short short8;   // 8 bf16 = 4 VGPRs
typedef __attribute__((ext_vector_type(4))) float f32x4;

static __device__ __forceinline__ unsigned short f2bf(float f) {
  union { float f; unsigned u; } x; x.f = f;
  unsigned r = x.u + 0x7FFFu + ((x.u >> 16) & 1u);   // round-to-nearest-even
  return (unsigned short)(r >> 16);
}

// brick element offset for element (row r_, k k_) in a brick file of depth Kd
static __device__ __forceinline__ long long brickoff(int r_, int k_, int Kd) {
  return (long long)(r_ >> 7) * ((long long)128 * Kd) +
         (long long)(k_ >> 5) * 4096 +
         (r_ & 127) * 32 +
         (((((k_ >> 3) & 3) ^ ((r_ >> 1) & 3))) << 3) +
         (k_ & 7);
}

// f32 row-major [M][1024] -> bf16 bricks (Kd=1024); two tensors per launch.
// Writes: dst[gid*16B] fully contiguous per instruction (this is the key).
__global__ __launch_bounds__(256) void cvt_brick_kernel(
    const float* __restrict__ s0, const float* __restrict__ s1,
    unsigned short* __restrict__ o0, unsigned short* __restrict__ o1,
    long long ngran) {
  const float* src = blockIdx.y ? s1 : s0;
  unsigned short* dst = blockIdx.y ? o1 : o0;
  long long gid = (long long)blockIdx.x * 256 + threadIdx.x;
  const long long stride = (long long)gridDim.x * 256;
  for (; gid < ngran; gid += stride) {
    const int tile = (int)(gid >> 14);          // 16384 granules per 128x1024 tile
    const int g2 = (int)(gid & 16383);
    const int ks = g2 >> 9;                     // k-slice
    const int rp = g2 & 511;
    const int r = rp >> 2;                      // row in tile
    const int p = rp & 3;                       // stored granule position
    const int g = p ^ ((r >> 1) & 3);           // source logical granule
    const float* sp = src + (long long)(tile * 128 + r) * 1024 + ks * 32 + g * 8;
    float4 u0 = ((const float4*)sp)[0];
    float4 u1 = ((const float4*)sp)[1];
    short8 pk;
    pk[0] = (short)f2bf(u0.x); pk[1] = (short)f2bf(u0.y);
    pk[2] = (short)f2bf(u0.z); pk[3] = (short)f2bf(u0.w);
    pk[4] = (short)f2bf(u1.x); pk[5] = (short)f2bf(u1.y);
    pk[6] = (short)f2bf(u1.z); pk[7] = (short)f2bf(u1.w);
    *(short8*)&dst[gid * 8] = pk;
  }
}

// all four C*C weights f32 -> bricks in one launch (blockIdx.y selects)
__global__ __launch_bounds__(256) void wcvt_brick_kernel(
    const float* __restrict__ w0, const float* __restrict__ w1,
    const float* __restrict__ w2, const float* __restrict__ w3,
    unsigned short* __restrict__ o0, unsigned short* __restrict__ o1,
    unsigned short* __restrict__ o2, unsigned short* __restrict__ o3) {
  const float* src; unsigned short* dst;
  switch (blockIdx.y) {
    case 0: src = w0; dst = o0; break;
    case 1: src = w1; dst = o1; break;
    case 2: src = w2; dst = o2; break;
    default: src = w3; dst = o3; break;
  }
  const int gid = blockIdx.x * 256 + threadIdx.x;   // 512*256 = 131072 exact
  const int tile = gid >> 14;
  const int g2 = gid & 16383;
  const int ks = g2 >> 9;
  const int rp = g2 & 511;
  const int r = rp >> 2;
  const int p = rp & 3;
  const int g = p ^ ((r >> 1) & 3);
  const float* sp = src + (long long)(tile * 128 + r) * 1024 + ks * 32 + g * 8;
  float4 u0 = ((const float4*)sp)[0];
  float4 u1 = ((const float4*)sp)[1];
  short8 pk;
  pk[0] = (short)f2bf(u0.x); pk[1] = (short)f2bf(u0.y);
  pk[2] = (short)f2bf(u0.z); pk[3] = (short)f2bf(u0.w);
  pk[4] = (short)f2bf(u1.x); pk[5] = (short)f2bf(u1.y);
  pk[6] = (short)f2bf(u1.z); pk[7] = (short)f2bf(u1.w);
  *(short8*)&dst[(long long)gid * 8] = pk;
}

#define EPI_BF16 0        // brick write, Kd = ldd
#define EPI_BF16_TRANS 1  // brick write transposed (Vt), Kd = ldd
#define EPI_EXP 2         // brick write exp(acc), Kd = ldd
#define EPI_PV 3          // brick write acc/rowsum, Kd = ldd
#define EPI_F32 4         // row-major f32, ld = ldd

// D = epilogue(A x B^T (+bias)(*scale)); A,B are BRICK files. No LDS.
// Block = (MFR*32) x (NFR*32), 4 waves 2x2, each wave MFR x NFR 16x16 frags.
template <int MFR, int NFR, int EPI, bool HAS_BIAS>
__global__ __launch_bounds__(256, (MFR * NFR >= 32) ? 2 : 3) void gemm_kernel(
    const unsigned short* __restrict__ A, const unsigned short* __restrict__ B,
    const float* __restrict__ bias, void* __restrict__ Dv,
    int NT, int ldaK, int ldbK, int ldd,
    long long sA, long long sBflat, int sBslice, int kOffB,
    long long sD, float scale) {
  constexpr int BM = MFR * 32;
  constexpr int BN = NFR * 32;

  // ---- XCD chunk swizzle (nwg % 8 == 0) ----
  int i = blockIdx.x + gridDim.x * (blockIdx.y + gridDim.y * blockIdx.z);
  const int nwg = gridDim.x * gridDim.y * gridDim.z;
  int v = (i & 7) * (nwg >> 3) + (i >> 3);
  const int by = v % gridDim.y;
  int u = v / gridDim.y;
  const int bx = u % gridDim.x;
  const int bz = u / gridDim.x;

  const int bm = bx * BM;
  const int bn = by * BN;
  const int tid = threadIdx.x;
  const int lane = tid & 63;
  const int wid = tid >> 6;
  const int wr = (wid >> 1) * (MFR * 16);
  const int wc = (wid & 1) * (NFR * 16);
  const int fr = lane & 15;
  const int hi = lane >> 4;
  // per-lane offset inside a fragment's contiguous 1KB block (intra-1KB perm)
  const int laneoff = fr * 32 + ((hi ^ ((fr >> 1) & 3)) << 3);

  f32x4 acc[MFR][NFR];
#pragma unroll
  for (int m = 0; m < MFR; ++m)
#pragma unroll
    for (int n = 0; n < NFR; ++n) acc[m][n] = (f32x4){0.f, 0.f, 0.f, 0.f};

  f32x4 asum[MFR];
  short8 ones;
#pragma unroll
  for (int m = 0; m < MFR; ++m) asum[m] = (f32x4){0.f, 0.f, 0.f, 0.f};
#pragma unroll
  for (int j = 0; j < 8; ++j) ones[j] = (short)0x3F80;  // bf16 1.0

  // wave's frags sit within ONE 128-row brick tile on each side:
  const unsigned short* Ap = A + bz * sA +
      (long long)((bm + wr) >> 7) * 128 * ldaK + (wr & 127) * 32 + laneoff;
  const unsigned short* Bp = B + bz * sBflat +
      (long long)((bn + wc) >> 7) * 128 * ldbK +
      (long long)(kOffB + bz * sBslice) * 4096 + (wc & 127) * 32 + laneoff;

  // 2-deep register double buffer, all statically indexed (rule #20)
  short8 a0[MFR], b0[NFR], a1[MFR], b1[NFR];
  auto LDA = [&](short8 (&d)[MFR], int t) {
    const unsigned short* p = Ap + (long long)t * 4096;
#pragma unroll
    for (int m = 0; m < MFR; ++m) d[m] = *(const short8*)(p + m * 512);
  };
  auto LDB = [&](short8 (&d)[NFR], int t) {
    const unsigned short* p = Bp + (long long)t * 4096;
#pragma unroll
    for (int n = 0; n < NFR; ++n) d[n] = *(const short8*)(p + n * 512);
  };
  auto FMA = [&](short8 (&a)[MFR], short8 (&b)[NFR]) {
#pragma unroll
    for (int m = 0; m < MFR; ++m)
#pragma unroll
      for (int n = 0; n < NFR; ++n)
        acc[m][n] = __builtin_amdgcn_mfma_f32_16x16x32_bf16(a[m], b[n],
                                                            acc[m][n], 0, 0, 0);
    if (EPI == EPI_PV) {
#pragma unroll
      for (int m = 0; m < MFR; ++m)
        asum[m] = __builtin_amdgcn_mfma_f32_16x16x32_bf16(a[m], ones,
                                                          asum[m], 0, 0, 0);
    }
  };

  LDA(a0, 0); LDB(b0, 0);
  LDA(a1, 1); LDB(b1, 1);
  for (int t = 0; t < NT - 2; t += 2) {
    FMA(a0, b0);
    LDA(a0, t + 2); LDB(b0, t + 2);
    FMA(a1, b1);
    LDA(a1, t + 3); LDB(b1, t + 3);
  }
  FMA(a0, b0);
  FMA(a1, b1);

  // ---- epilogue: C/D frag layout col=lane&15, row=(lane>>4)*4+j ----
  const int cr = hi * 4;
  const int cc = fr;
#pragma unroll
  for (int m = 0; m < MFR; ++m) {
    const int row0 = bm + wr + m * 16 + cr;
#pragma unroll
    for (int n = 0; n < NFR; ++n) {
      const int col = bn + wc + n * 16 + cc;
      const float bv = HAS_BIAS ? bias[col] : 0.f;
      if (EPI == EPI_F32) {
        float* D = (float*)Dv + bz * sD;
#pragma unroll
        for (int j = 0; j < 4; ++j)
          D[(long long)(row0 + j) * ldd + col] = acc[m][n][j] + bv;
      } else if (EPI == EPI_BF16) {
        unsigned short* D = (unsigned short*)Dv + bz * sD;
#pragma unroll
        for (int j = 0; j < 4; ++j)
          D[brickoff(row0 + j, col, ldd)] = f2bf((acc[m][n][j] + bv) * scale);
      } else if (EPI == EPI_BF16_TRANS) {
        unsigned short* D = (unsigned short*)Dv + bz * sD;
#pragma unroll
        for (int j = 0; j < 4; ++j)
          D[brickoff(col, row0 + j, ldd)] = f2bf((acc[m][n][j] + bv) * scale);
      } else if (EPI == EPI_EXP) {
        unsigned short* D = (unsigned short*)Dv + bz * sD;
#pragma unroll
        for (int j = 0; j < 4; ++j)
          D[brickoff(row0 + j, col, ldd)] = f2bf(__expf(acc[m][n][j]));
      } else {  // EPI_PV
        unsigned short* D = (unsigned short*)Dv + bz * sD;
#pragma unroll
        for (int j = 0; j < 4; ++j) {
          const float li = 1.f / asum[m][j];
          D[brickoff(row0 + j, col, ldd)] = f2bf(acc[m][n][j] * li);
        }
      }
    }
  }
}

extern "C" void kernel_launch(void* const* d_in, const int* in_sizes, int n_in,
                              void* d_out, int out_size, void* d_ws, size_t ws_size,
                              hipStream_t stream) {
  (void)in_sizes; (void)n_in; (void)out_size;
  const float* input  = (const float*)d_in[0];
  const float* memory = (const float*)d_in[1];
  const float* Wq = (const float*)d_in[2];
  const float* bq = (const float*)d_in[3];
  const float* Wk = (const float*)d_in[4];
  const float* bk = (const float*)d_in[5];
  const float* Wv = (const float*)d_in[6];
  const float* bv = (const float*)d_in[7];
  const float* Wo = (const float*)d_in[8];
  const float* bo = (const float*)d_in[9];
  float* out = (float*)d_out;

  const int S = 2048, C = 1024;
  const int CB = 4;
  const long long BS = 16384;
  const long long N_IN = BS * C;        // 16,777,216
  const long long N_W  = (long long)C * C;

  char* p = (char*)d_ws;
  auto alloc = [&](size_t bytes) {
    char* r = p;
    p += (bytes + 255) & ~(size_t)255;
    return r;
  };
  unsigned short* wqb  = (unsigned short*)alloc(N_W * 2);
  unsigned short* wkb  = (unsigned short*)alloc(N_W * 2);
  unsigned short* wvb  = (unsigned short*)alloc(N_W * 2);
  unsigned short* wob  = (unsigned short*)alloc(N_W * 2);
  unsigned short* Qb   = (unsigned short*)alloc(N_IN * 2);   // bricks Kd=1024; later sel
  unsigned short* Kb   = (unsigned short*)alloc(N_IN * 2);   // bricks Kd=1024
  unsigned short* Xb   = (unsigned short*)alloc(N_IN * 2);   // memb bricks, then Pt
  if ((size_t)(p - (char*)d_ws) > ws_size) return;

  unsigned short* Vt  = (unsigned short*)d_out;          // V bricks (rows=c, Kd=16384)
  unsigned short* inb = (unsigned short*)d_out + N_IN;   // input bricks Kd=1024
  unsigned short* memb = Xb;
  unsigned short* Pt   = Xb;                             // P~ bricks Kd=2048 (CB batches)

  // ---- f32 -> bf16 bricks ----
  wcvt_brick_kernel<<<dim3(512, 4, 1), 256, 0, stream>>>(Wq, Wk, Wv, Wo,
                                                         wqb, wkb, wvb, wob);
  cvt_brick_kernel<<<dim3(2048, 2, 1), 256, 0, stream>>>(memory, input, memb, inb,
                                                         N_IN / 8);

  const float depth_scale = 0.03125f;  // 1024^-0.5

  // ---- projections (NT=32): 128x256 blocks, grid (128,4)=512 ----
  gemm_kernel<4, 8, EPI_BF16, true><<<dim3(128, 4, 1), 256, 0, stream>>>(
      memb, wkb, bk, Kb, 32, C, C, C, 0, 0, 0, 0, 0, 1.0f);
  gemm_kernel<4, 8, EPI_BF16_TRANS, true><<<dim3(128, 4, 1), 256, 0, stream>>>(
      memb, wvb, bv, Vt, 32, C, C, (int)BS, 0, 0, 0, 0, 0, 1.0f);
  gemm_kernel<4, 8, EPI_BF16, true><<<dim3(128, 4, 1), 256, 0, stream>>>(
      inb, wqb, bq, Qb, 32, C, C, C, 0, 0, 0, 0, 0, depth_scale);

  // ---- attention, CB=4 batches per chunk (memb dead -> Pt) ----
  for (int c = 0; c < 8 / CB; ++c) {
    const long long qoff = (long long)c * CB * S * C;
    // P~ = exp(Q[b] @ K[b]^T) -> Pt bricks Kd=2048; grid (16,8,4)=512
    gemm_kernel<4, 8, EPI_EXP, false><<<dim3(16, 8, CB), 256, 0, stream>>>(
        Qb + qoff, Kb + qoff, nullptr, Pt,
        32, C, C, S, (long long)S * C, (long long)S * C, 0, 0,
        (long long)S * S, 1.0f);
    // sel[b] = (P~ @ V[b]) / rowsum -> sel bricks over dead Q rows; grid (16,8,4)=512
    gemm_kernel<4, 4, EPI_PV, false><<<dim3(16, 8, CB), 256, 0, stream>>>(
        Pt, Vt, nullptr, Qb + qoff,
        64, S, (int)BS, C, (long long)S * S, 0, 64, c * CB * 64,
        (long long)S * C, 1.0f);
  }

  // ---- out = sel @ Wo^T + bo -> f32 row-major d_out ----
  gemm_kernel<4, 8, EPI_F32, true><<<dim3(128, 4, 1), 256, 0, stream>>>(
      Qb, wob, bo, out, 32, C, C, C, 0, 0, 0, 0, 0, 1.0f);
}